// Round 9
// baseline (248.984 us; speedup 1.0000x reference)
//
#include <hip/hip_runtime.h>

typedef unsigned short u16;
typedef unsigned int u32;
typedef unsigned long long u64;
typedef __attribute__((ext_vector_type(2))) unsigned long long u64x2;
typedef __attribute__((ext_vector_type(4))) unsigned short u16x4;
typedef __attribute__((ext_vector_type(8))) __bf16 bf16x8;
typedef __attribute__((ext_vector_type(4))) float f32x4;
typedef __attribute__((ext_vector_type(2))) float f32x2;

#define DEV static __device__ __forceinline__
#define LOG2E 1.4426950408889634f

DEV u16 f2bf(float f) { __bf16 h = (__bf16)f; return __builtin_bit_cast(u16, h); }

// Problem constants
#define BB   2
#define LLEN 2048
#define DDIM 1024
#define HH   16
#define DH   64
#define MTOT 4096   // B*L
#define N3   3072   // 3*D

// ---------------- async global->LDS ----------------
DEV void gl16(const void* g, void* l) {
  __builtin_amdgcn_global_load_lds(
      (const __attribute__((address_space(1))) void*)g,
      (__attribute__((address_space(3))) void*)l, 16, 0, 0);
}
DEV void gl4(const void* g, void* l) {
  __builtin_amdgcn_global_load_lds(
      (const __attribute__((address_space(1))) void*)g,
      (__attribute__((address_space(3))) void*)l, 4, 0, 0);
}

// Stage a 64-row x 128B tile into linear LDS with XOR swizzle on row bits
// {0,1,3}: LDS[row*128 + cb] = G[row][cb ^ (swz3(row)<<4)],
// swz3(row) = (row&3) | (((row>>3)&1)<<2).
DEV void stage64(const u16* org, size_t gsb, u16* lds, int lane, int wid) {
#pragma unroll
  for (int j = 0; j < 2; j++) {
    int inst = wid * 2 + j;
    int r8 = lane >> 3;                      // row&7
    int row = inst * 8 + r8;
    int s = (r8 & 3) | ((inst & 1) << 2);    // == swz3(row)
    const char* src = (const char*)org + (size_t)row * gsb +
                      (((lane & 7) ^ s) << 4);
    gl16(src, (char*)lds + inst * 1024);
  }
}
DEV bf16x8 read128s(const u16* tile, int row, int colb) {
  return *reinterpret_cast<const bf16x8*>(
      (const char*)tile + row * 128 +
      (colb ^ (((row & 3) | (((row >> 3) & 1) << 2)) << 4)));
}

// Stage a 128-row x 64B tile: LDS[row*64 + cb] = G[row][cb ^ ((row&3)<<4)].
DEV void stage128x32(const u16* org, size_t gsb, u16* lds, int lane, int wid) {
#pragma unroll
  for (int j = 0; j < 2; j++) {
    int inst = wid + j * 4;
    int r16 = lane >> 2;
    const char* src = (const char*)org + (size_t)(inst * 16 + r16) * gsb +
                      ((((lane & 3) ^ (r16 & 3))) << 4);
    gl16(src, (char*)lds + inst * 1024);
  }
}
DEV bf16x8 read64(const u16* tile, int row, int colb) {
  return *reinterpret_cast<const bf16x8*>(
      (const char*)tile + row * 64 + (colb ^ ((row & 3) << 4)));
}

// ---------------- W [K][N] fp32 -> WT [N][K] bf16 ----------------
__global__ __launch_bounds__(256) void k_transpose_w(const float* __restrict__ W,
                                                     u16* __restrict__ WT,
                                                     int K, int N) {
  __shared__ float s[32][33];
  int k0 = blockIdx.x * 32, n0 = blockIdx.y * 32;
  int tx = threadIdx.x & 31, ty = threadIdx.x >> 5;
#pragma unroll
  for (int i = 0; i < 4; i++)
    s[ty + i * 8][tx] = W[(k0 + ty + i * 8) * (size_t)N + n0 + tx];
  __syncthreads();
#pragma unroll
  for (int i = 0; i < 4; i++)
    WT[(size_t)(n0 + ty + i * 8) * K + k0 + tx] = f2bf(s[tx][ty + i * 8]);
}

// ---------------- phase + x->bf16 fused ----------------
// ppk[bh][l] = {pk, -rs*log2e*pk^2 (or -1e9 if masked)}; also emits x_bf.
__global__ __launch_bounds__(256) void k_phase(const float* __restrict__ x,
                                               const float* __restrict__ Wp,
                                               const float* __restrict__ bp,
                                               const float* __restrict__ pscale,
                                               const float* __restrict__ rscale,
                                               const int* __restrict__ mask,
                                               f32x2* __restrict__ ppk,
                                               u16* __restrict__ x_bf) {
  int m = blockIdx.x;
  int t = threadIdx.x;
  int h = t & 15, j = t >> 4;
  const float* xr = x + (size_t)m * DDIM;
  u16* xbr = x_bf + (size_t)m * DDIM;
  const float* wpb = Wp + h;
  float acc = 0.f;
#pragma unroll 4
  for (int kk4 = 0; kk4 < 16; kk4++) {
    int k0 = j * 64 + kk4 * 4;
    f32x4 xv = *reinterpret_cast<const f32x4*>(xr + k0);
    acc = fmaf(xv.x, wpb[(k0 + 0) * HH], acc);
    acc = fmaf(xv.y, wpb[(k0 + 1) * HH], acc);
    acc = fmaf(xv.z, wpb[(k0 + 2) * HH], acc);
    acc = fmaf(xv.w, wpb[(k0 + 3) * HH], acc);
    if (h == 0) {
      u16x4 o;
      o.x = f2bf(xv.x); o.y = f2bf(xv.y); o.z = f2bf(xv.z); o.w = f2bf(xv.w);
      *reinterpret_cast<u16x4*>(xbr + k0) = o;
    }
  }
  __shared__ float s[16][17];
  s[j][h] = acc;
  __syncthreads();
  if (t < 16) {
    float sum = 0.f;
#pragma unroll
    for (int jj = 0; jj < 16; jj++) sum += s[jj][t];
    float v = tanhf((*pscale) * (sum + bp[t]));
    int b = m >> 11, l = m & (LLEN - 1);
    float kb = (mask[m] == 0) ? -1.0e9f : (-(*rscale) * LOG2E) * v * v;
    f32x2 o; o.x = v; o.y = kb;
    ppk[((size_t)(b * HH + t)) * LLEN + l] = o;
  }
}

// ---------------- 128x128 bf16 MFMA GEMM (dbuf + global_load_lds) ----------------
// QKV mode: column tiles with n0 >= 2*DDIM (the V third) are written directly
// to vT[b][h][dh][l] (transposed, u64-packed) instead of the qkv buffer —
// fuses the old k_vtrans kernel. Values identical: f2bf(acc+bias).
template <bool BF16_OUT, bool QKV>
__global__ __launch_bounds__(256) void k_gemm(const u16* __restrict__ A,
                                              const u16* __restrict__ BT,
                                              const float* __restrict__ bias,
                                              void* __restrict__ C,
                                              u16* __restrict__ vT,
                                              int M, int N, int K) {
  __shared__ __attribute__((aligned(16))) u16 sA[2][128 * 32];
  __shared__ __attribute__((aligned(16))) u16 sB[2][128 * 32];
  int m0 = blockIdx.x * 128, n0 = blockIdx.y * 128;
  int t = threadIdx.x, lane = t & 63, wid = t >> 6;
  int wm = wid >> 1, wn = wid & 1;
  int lc = lane & 15, lg = lane >> 4;

  const u16* Ao = A + (size_t)m0 * K;
  const u16* Bo = BT + (size_t)n0 * K;

  f32x4 acc[4][4] = {};
  stage128x32(Ao, (size_t)K * 2, sA[0], lane, wid);
  stage128x32(Bo, (size_t)K * 2, sB[0], lane, wid);
  __syncthreads();
  int cur = 0;
  int NT = K >> 5;
  for (int kt = 0; kt < NT; kt++) {
    if (kt + 1 < NT) {
      stage128x32(Ao + (kt + 1) * 32, (size_t)K * 2, sA[cur ^ 1], lane, wid);
      stage128x32(Bo + (kt + 1) * 32, (size_t)K * 2, sB[cur ^ 1], lane, wid);
    }
    bf16x8 af[4], bfr[4];
#pragma unroll
    for (int i = 0; i < 4; i++) af[i] = read64(sA[cur], wm * 64 + i * 16 + lc, lg * 16);
#pragma unroll
    for (int j = 0; j < 4; j++) bfr[j] = read64(sB[cur], wn * 64 + j * 16 + lc, lg * 16);
    __builtin_amdgcn_s_setprio(1);
#pragma unroll
    for (int i = 0; i < 4; i++)
#pragma unroll
      for (int j = 0; j < 4; j++)
        acc[i][j] = __builtin_amdgcn_mfma_f32_16x16x32_bf16(af[i], bfr[j], acc[i][j], 0, 0, 0);
    __builtin_amdgcn_s_setprio(0);
    __syncthreads();
    cur ^= 1;
  }

  int rg = lane >> 4;
  if (QKV && n0 >= 2 * DDIM) {
    // V third -> vT transposed
#pragma unroll
    for (int i = 0; i < 4; i++) {
      int rowb = m0 + wm * 64 + i * 16 + rg * 4;       // 4 consecutive rows
      int bb = rowb >> 11, l = rowb & (LLEN - 1);
#pragma unroll
      for (int j = 0; j < 4; j++) {
        int vcol = n0 - 2 * DDIM + wn * 64 + j * 16 + lc;  // h*64+dh
        float bv = bias[n0 + wn * 64 + j * 16 + lc];
        u16 tmp[4];
#pragma unroll
        for (int r = 0; r < 4; r++) tmp[r] = f2bf(acc[i][j][r] + bv);
        *reinterpret_cast<u64*>(&vT[(size_t)vcol * LLEN + bb * (HH * DH * LLEN) + l]) =
            *reinterpret_cast<u64*>(tmp);
      }
    }
    return;
  }
#pragma unroll
  for (int i = 0; i < 4; i++) {
#pragma unroll
    for (int j = 0; j < 4; j++) {
      int col = n0 + wn * 64 + j * 16 + lc;
      float bv = bias[col];
#pragma unroll
      for (int r = 0; r < 4; r++) {
        int row = m0 + wm * 64 + i * 16 + rg * 4 + r;
        float v = acc[i][j][r] + bv;
        if (BF16_OUT)
          ((u16*)C)[(size_t)row * N + col] = f2bf(v);
        else
          ((float*)C)[(size_t)row * N + col] = v;
      }
    }
  }
}

// ---------------- flash attention, swapped QK^T, counted-vmcnt pipeline ----------------
// Key permutation: QK^T mfma #blk uses K rows f(blk,m)=32*(blk>>1)+8*(m>>2)+
// 4*(blk&1)+(m&3). Lane (lc,lg) owns S[q=qb+lc][key=f(blk,lg*4+r)] in
// sv[blk][r] == PV A-frag element order — P->PV is in-lane bf16 casts only.
// Pipeline: 6 VMEM ops per wave per tile; s_waitcnt vmcnt(6) keeps the next
// tile's loads in flight. Main loop manually unrolled x2 (literal buffer
// indices -> compile-time LDS offsets, no cur-flip arithmetic).
// XCD remap: lin%8 == XCD (heuristic); each XCD gets 4 contiguous bh ->
// K/V working set 2MB < 4MB L2.
__global__ __launch_bounds__(256, 4) void k_attn(const u16* __restrict__ qkv,
                                                 const u16* __restrict__ vT,
                                                 const f32x2* __restrict__ ppk,
                                                 const float* __restrict__ rscale_p,
                                                 u16* __restrict__ attn_out) {
  __shared__ __attribute__((aligned(16))) u16 kS[2][64 * 64];
  __shared__ __attribute__((aligned(16))) u16 vS[2][64 * 64];
  __shared__ __attribute__((aligned(16))) float ppS[2][128];

  int lin = blockIdx.y * 32 + blockIdx.x;
  int xcd = lin & 7, slot = lin >> 3;
  int bh = xcd * 4 + (slot >> 5);
  int q0 = (slot & 31) * 64;
  int b = bh >> 4, h = bh & 15;
  int t = threadIdx.x, lane = t & 63, wid = t >> 6;
  int qb = q0 + wid * 16;
  int lc = lane & 15, lg = lane >> 4;

  const float rs2 = (*rscale_p) * LOG2E;
  const float c1 = 0.125f * LOG2E;
  const f32x2* pprow = ppk + (size_t)bh * LLEN;
  const float* pprowf = (const float*)pprow;

  // Q B-fragment: lane holds Q[qb+lc][dh=lg*8+j]
  bf16x8 qf0, qf1;
  {
    const u16* qp = &qkv[(size_t)(b * LLEN + qb + lc) * N3 + h * DH + lg * 8];
    qf0 = *reinterpret_cast<const bf16x8*>(qp);
    qf1 = *reinterpret_cast<const bf16x8*>(qp + 32);
  }
  float wq = 2.f * rs2 * pprow[qb + lc].x;   // per-lane scalar (q = lc)

  const u16* kg = qkv + (size_t)(b * LLEN) * N3 + DDIM + h * DH;  // rows: key
  const u16* vg = vT + (size_t)bh * DH * LLEN;                    // rows: dh

  // prologue: stage tile 0 (6 VMEM ops per wave)
  stage64(kg, (size_t)N3 * 2, kS[0], lane, wid);
  stage64(vg, (size_t)LLEN * 2, vS[0], lane, wid);
  gl4(pprowf + lane, &ppS[0][0]);
  gl4(pprowf + 64 + lane, &ppS[0][64]);

  f32x4 o[4] = {};
  float mrow = -1e30f, lrow = 0.f;
  int arow = ((lc >> 2) << 3) | (lc & 3);    // f(blk,lc) base

#define ATTN_STEP(KB, CUR)                                                     \
  do {                                                                         \
    if ((KB) + 64 < LLEN) {                                                    \
      stage64(kg + (size_t)((KB) + 64) * N3, (size_t)N3 * 2, kS[(CUR) ^ 1],    \
              lane, wid);                                                      \
      stage64(vg + (KB) + 64, (size_t)LLEN * 2, vS[(CUR) ^ 1], lane, wid);     \
      const float* pt_ = pprowf + (size_t)((KB) + 64) * 2;                     \
      gl4(pt_ + lane, &ppS[(CUR) ^ 1][0]);                                     \
      gl4(pt_ + 64 + lane, &ppS[(CUR) ^ 1][64]);                               \
      asm volatile("s_waitcnt vmcnt(6)" ::: "memory");                         \
    } else {                                                                   \
      asm volatile("s_waitcnt vmcnt(0)" ::: "memory");                         \
    }                                                                          \
    __builtin_amdgcn_s_barrier();                                              \
    f32x4 sv[4];                                                               \
    _Pragma("unroll") for (int blk = 0; blk < 4; blk++) {                      \
      int krow = arow + ((blk & 2) << 4) + ((blk & 1) << 2);                   \
      bf16x8 kf0 = read128s(kS[CUR], krow, lg * 16);                           \
      bf16x8 kf1 = read128s(kS[CUR], krow, 64 + lg * 16);                      \
      f32x4 z = {};                                                            \
      __builtin_amdgcn_s_setprio(1);                                           \
      z = __builtin_amdgcn_mfma_f32_16x16x32_bf16(kf0, qf0, z, 0, 0, 0);       \
      z = __builtin_amdgcn_mfma_f32_16x16x32_bf16(kf1, qf1, z, 0, 0, 0);       \
      __builtin_amdgcn_s_setprio(0);                                           \
      sv[blk] = z;                                                             \
    }                                                                          \
    {                                                                          \
      const float* pt_ = &ppS[CUR][0];                                         \
      _Pragma("unroll") for (int blk = 0; blk < 4; blk++) {                    \
        int off2 = (((blk & 2) << 4) + ((blk & 1) << 2) + lg * 8) * 2;         \
        f32x4 p0 = *reinterpret_cast<const f32x4*>(pt_ + off2);                \
        f32x4 p1 = *reinterpret_cast<const f32x4*>(pt_ + off2 + 4);            \
        sv[blk][0] = fmaf(sv[blk][0], c1, fmaf(wq, p0.x, p0.y));               \
        sv[blk][1] = fmaf(sv[blk][1], c1, fmaf(wq, p0.z, p0.w));               \
        sv[blk][2] = fmaf(sv[blk][2], c1, fmaf(wq, p1.x, p1.y));               \
        sv[blk][3] = fmaf(sv[blk][3], c1, fmaf(wq, p1.z, p1.w));               \
      }                                                                        \
    }                                                                          \
    float rm = sv[0][0];                                                       \
    _Pragma("unroll") for (int blk = 0; blk < 4; blk++)                        \
        _Pragma("unroll") for (int r = 0; r < 4; r++)                          \
            rm = fmaxf(rm, sv[blk][r]);                                        \
    rm = fmaxf(rm, __shfl_xor(rm, 16, 64));                                    \
    rm = fmaxf(rm, __shfl_xor(rm, 32, 64));                                    \
    if (!__all(rm <= mrow + 8.f)) {                                            \
      float mn = fmaxf(mrow, rm);                                              \
      float al = __builtin_amdgcn_exp2f(mrow - mn);                            \
      mrow = mn;                                                               \
      lrow *= al;                                                              \
      float ao0 = __shfl(al, lg * 4 + 0, 16);                                  \
      float ao1 = __shfl(al, lg * 4 + 1, 16);                                  \
      float ao2 = __shfl(al, lg * 4 + 2, 16);                                  \
      float ao3 = __shfl(al, lg * 4 + 3, 16);                                  \
      _Pragma("unroll") for (int d = 0; d < 4; d++) {                          \
        o[d][0] *= ao0; o[d][1] *= ao1; o[d][2] *= ao2; o[d][3] *= ao3;        \
      }                                                                        \
    }                                                                          \
    float ssum = 0.f;                                                          \
    _Pragma("unroll") for (int blk = 0; blk < 4; blk++)                        \
        _Pragma("unroll") for (int r = 0; r < 4; r++) {                        \
      float p = __builtin_amdgcn_exp2f(sv[blk][r] - mrow);                     \
      sv[blk][r] = p;                                                          \
      ssum += p;                                                               \
    }                                                                          \
    ssum += __shfl_xor(ssum, 16, 64);                                          \
    ssum += __shfl_xor(ssum, 32, 64);                                          \
    lrow += ssum;                                                              \
    bf16x8 pa0, pa1;                                                           \
    _Pragma("unroll") for (int r = 0; r < 4; r++) {                            \
      pa0[r] = (__bf16)sv[0][r];                                               \
      pa0[4 + r] = (__bf16)sv[1][r];                                           \
      pa1[r] = (__bf16)sv[2][r];                                               \
      pa1[4 + r] = (__bf16)sv[3][r];                                           \
    }                                                                          \
    _Pragma("unroll") for (int d = 0; d < 4; d++) {                            \
      bf16x8 vb0 = read128s(vS[CUR], d * 16 + lc, lg * 16);                    \
      bf16x8 vb1 = read128s(vS[CUR], d * 16 + lc, 64 + lg * 16);               \
      __builtin_amdgcn_s_setprio(1);                                           \
      o[d] = __builtin_amdgcn_mfma_f32_16x16x32_bf16(pa0, vb0, o[d], 0, 0, 0); \
      o[d] = __builtin_amdgcn_mfma_f32_16x16x32_bf16(pa1, vb1, o[d], 0, 0, 0); \
      __builtin_amdgcn_s_setprio(0);                                           \
    }                                                                          \
    __builtin_amdgcn_s_barrier();                                              \
  } while (0)

  for (int kt = 0; kt < LLEN / 64; kt += 2) {
    ATTN_STEP(kt * 64, 0);
    ATTN_STEP(kt * 64 + 64, 1);
  }
#undef ATTN_STEP

  // epilogue: O rows are q=qb+lg*4+r, cols dh=d*16+lc; l lives at lane lc=q
  float linv = 1.0f / lrow;
  float li0 = __shfl(linv, lg * 4 + 0, 16);
  float li1 = __shfl(linv, lg * 4 + 1, 16);
  float li2 = __shfl(linv, lg * 4 + 2, 16);
  float li3 = __shfl(linv, lg * 4 + 3, 16);
#pragma unroll
  for (int d = 0; d < 4; d++) {
    int col = h * DH + d * 16 + lc;
    size_t base = (size_t)(b * LLEN + qb + lg * 4) * DDIM + col;
    attn_out[base] = f2bf(o[d][0] * li0);
    attn_out[base + DDIM] = f2bf(o[d][1] * li1);
    attn_out[base + 2 * DDIM] = f2bf(o[d][2] * li2);
    attn_out[base + 3 * DDIM] = f2bf(o[d][3] * li3);
  }
}

extern "C" void kernel_launch(void* const* d_in, const int* in_sizes, int n_in,
                              void* d_out, int out_size, void* d_ws, size_t ws_size,
                              hipStream_t stream) {
  const float* x       = (const float*)d_in[0];
  const int*   mask    = (const int*)d_in[1];
  const float* W_qkv   = (const float*)d_in[2];
  const float* b_qkv   = (const float*)d_in[3];
  const float* W_out   = (const float*)d_in[4];
  const float* b_out   = (const float*)d_in[5];
  const float* W_phase = (const float*)d_in[6];
  const float* b_phase = (const float*)d_in[7];
  const float* rscale  = (const float*)d_in[8];
  const float* pscale  = (const float*)d_in[9];
  float* out = (float*)d_out;

  char* ws = (char*)d_ws;
  u16* x_bf     = (u16*)(ws + 0);           //  8.0 MB
  u16* wt_qkv   = (u16*)(ws + 8388608);     //  6.0 MB
  u16* wt_out   = (u16*)(ws + 14680064);    //  2.0 MB
  u16* qkv      = (u16*)(ws + 16777216);    // 24.0 MB (v third unused)
  u16* vT       = (u16*)(ws + 41943040);    //  8.0 MB
  u16* attn_out = (u16*)(ws + 50331648);    //  8.0 MB
  f32x2* ppk    = (f32x2*)(ws + 58720256);  //  0.5 MB

  k_transpose_w<<<dim3(DDIM / 32, N3 / 32), 256, 0, stream>>>(W_qkv, wt_qkv, DDIM, N3);
  k_transpose_w<<<dim3(DDIM / 32, DDIM / 32), 256, 0, stream>>>(W_out, wt_out, DDIM, DDIM);
  k_phase<<<MTOT, 256, 0, stream>>>(x, W_phase, b_phase, pscale, rscale, mask, ppk, x_bf);
  k_gemm<true, true><<<dim3(MTOT / 128, N3 / 128), 256, 0, stream>>>(
      x_bf, wt_qkv, b_qkv, qkv, vT, MTOT, N3, DDIM);
  k_attn<<<dim3(LLEN / 64, BB * HH), 256, 0, stream>>>(
      qkv, vT, ppk, rscale, attn_out);
  k_gemm<false, false><<<dim3(MTOT / 128, DDIM / 128), 256, 0, stream>>>(
      attn_out, wt_out, b_out, out, nullptr, MTOT, DDIM, DDIM);
}

// Round 10
// 232.862 us; speedup vs baseline: 1.0692x; 1.0692x over previous
//
#include <hip/hip_runtime.h>

typedef unsigned short u16;
typedef unsigned int u32;
typedef unsigned long long u64;
typedef __attribute__((ext_vector_type(2))) unsigned long long u64x2;
typedef __attribute__((ext_vector_type(4))) unsigned short u16x4;
typedef __attribute__((ext_vector_type(8))) __bf16 bf16x8;
typedef __attribute__((ext_vector_type(4))) float f32x4;
typedef __attribute__((ext_vector_type(2))) float f32x2;

#define DEV static __device__ __forceinline__
#define LOG2E 1.4426950408889634f

DEV u16 f2bf(float f) { __bf16 h = (__bf16)f; return __builtin_bit_cast(u16, h); }

// Problem constants
#define BB   2
#define LLEN 2048
#define DDIM 1024
#define HH   16
#define DH   64
#define MTOT 4096   // B*L
#define N3   3072   // 3*D

// ---------------- async global->LDS ----------------
DEV void gl16(const void* g, void* l) {
  __builtin_amdgcn_global_load_lds(
      (const __attribute__((address_space(1))) void*)g,
      (__attribute__((address_space(3))) void*)l, 16, 0, 0);
}
DEV void gl4(const void* g, void* l) {
  __builtin_amdgcn_global_load_lds(
      (const __attribute__((address_space(1))) void*)g,
      (__attribute__((address_space(3))) void*)l, 4, 0, 0);
}

// Stage a 64-row x 128B tile into linear LDS with XOR swizzle on row bits
// {0,1,3}: LDS[row*128 + cb] = G[row][cb ^ (swz3(row)<<4)],
// swz3(row) = (row&3) | (((row>>3)&1)<<2).
DEV void stage64(const u16* org, size_t gsb, u16* lds, int lane, int wid) {
#pragma unroll
  for (int j = 0; j < 2; j++) {
    int inst = wid * 2 + j;
    int r8 = lane >> 3;                      // row&7
    int row = inst * 8 + r8;
    int s = (r8 & 3) | ((inst & 1) << 2);    // == swz3(row)
    const char* src = (const char*)org + (size_t)row * gsb +
                      (((lane & 7) ^ s) << 4);
    gl16(src, (char*)lds + inst * 1024);
  }
}
DEV bf16x8 read128s(const u16* tile, int row, int colb) {
  return *reinterpret_cast<const bf16x8*>(
      (const char*)tile + row * 128 +
      (colb ^ (((row & 3) | (((row >> 3) & 1) << 2)) << 4)));
}

// Stage a 128-row x 64B tile: LDS[row*64 + cb] = G[row][cb ^ ((row&3)<<4)].
DEV void stage128x32(const u16* org, size_t gsb, u16* lds, int lane, int wid) {
#pragma unroll
  for (int j = 0; j < 2; j++) {
    int inst = wid + j * 4;
    int r16 = lane >> 2;
    const char* src = (const char*)org + (size_t)(inst * 16 + r16) * gsb +
                      ((((lane & 3) ^ (r16 & 3))) << 4);
    gl16(src, (char*)lds + inst * 1024);
  }
}
DEV bf16x8 read64(const u16* tile, int row, int colb) {
  return *reinterpret_cast<const bf16x8*>(
      (const char*)tile + row * 64 + (colb ^ ((row & 3) << 4)));
}

// ---------------- W [K][N] fp32 -> WT [N][K] bf16 ----------------
__global__ __launch_bounds__(256) void k_transpose_w(const float* __restrict__ W,
                                                     u16* __restrict__ WT,
                                                     int K, int N) {
  __shared__ float s[32][33];
  int k0 = blockIdx.x * 32, n0 = blockIdx.y * 32;
  int tx = threadIdx.x & 31, ty = threadIdx.x >> 5;
#pragma unroll
  for (int i = 0; i < 4; i++)
    s[ty + i * 8][tx] = W[(k0 + ty + i * 8) * (size_t)N + n0 + tx];
  __syncthreads();
#pragma unroll
  for (int i = 0; i < 4; i++)
    WT[(size_t)(n0 + ty + i * 8) * K + k0 + tx] = f2bf(s[tx][ty + i * 8]);
}

// ---------------- phase + x->bf16 fused ----------------
// ppk[bh][l] = {pk, -rs*log2e*pk^2 (or -1e9 if masked)}; also emits x_bf
// via a separate fully-coalesced pass (256 threads x 4 elems = row).
__global__ __launch_bounds__(256) void k_phase(const float* __restrict__ x,
                                               const float* __restrict__ Wp,
                                               const float* __restrict__ bp,
                                               const float* __restrict__ pscale,
                                               const float* __restrict__ rscale,
                                               const int* __restrict__ mask,
                                               f32x2* __restrict__ ppk,
                                               u16* __restrict__ x_bf) {
  int m = blockIdx.x;
  int t = threadIdx.x;
  const float* xr = x + (size_t)m * DDIM;
  u16* xbr = x_bf + (size_t)m * DDIM;
  // coalesced x -> bf16
  {
    f32x4 xv = *reinterpret_cast<const f32x4*>(xr + t * 4);
    u16x4 o;
    o.x = f2bf(xv.x); o.y = f2bf(xv.y); o.z = f2bf(xv.z); o.w = f2bf(xv.w);
    *reinterpret_cast<u16x4*>(xbr + t * 4) = o;
  }
  int h = t & 15, j = t >> 4;
  const float* wpb = Wp + h;
  float acc = 0.f;
#pragma unroll 4
  for (int kk4 = 0; kk4 < 16; kk4++) {
    int k0 = j * 64 + kk4 * 4;
    f32x4 xv = *reinterpret_cast<const f32x4*>(xr + k0);
    acc = fmaf(xv.x, wpb[(k0 + 0) * HH], acc);
    acc = fmaf(xv.y, wpb[(k0 + 1) * HH], acc);
    acc = fmaf(xv.z, wpb[(k0 + 2) * HH], acc);
    acc = fmaf(xv.w, wpb[(k0 + 3) * HH], acc);
  }
  __shared__ float s[16][17];
  s[j][h] = acc;
  __syncthreads();
  if (t < 16) {
    float sum = 0.f;
#pragma unroll
    for (int jj = 0; jj < 16; jj++) sum += s[jj][t];
    float v = tanhf((*pscale) * (sum + bp[t]));
    int b = m >> 11, l = m & (LLEN - 1);
    float kb = (mask[m] == 0) ? -1.0e9f : (-(*rscale) * LOG2E) * v * v;
    f32x2 o; o.x = v; o.y = kb;
    ppk[((size_t)(b * HH + t)) * LLEN + l] = o;
  }
}

// ---------------- 128x128 bf16 MFMA GEMM (dbuf + global_load_lds) ----------------
// QKV mode: column tiles with n0 >= 2*DDIM (the V third) are transposed
// through LDS (reusing the staging buffers after the last barrier) and
// written to vT[b][h][dh][l] with 128B-contiguous-per-row coalescing.
// Values identical: f2bf(acc+bias).
template <bool BF16_OUT, bool QKV>
__global__ __launch_bounds__(256) void k_gemm(const u16* __restrict__ A,
                                              const u16* __restrict__ BT,
                                              const float* __restrict__ bias,
                                              void* __restrict__ C,
                                              u16* __restrict__ vT,
                                              int M, int N, int K) {
  __shared__ __attribute__((aligned(16))) u16 sS[4][128 * 32];  // sA=sS[0..1], sB=sS[2..3]
  int m0 = blockIdx.x * 128, n0 = blockIdx.y * 128;
  int t = threadIdx.x, lane = t & 63, wid = t >> 6;
  int wm = wid >> 1, wn = wid & 1;
  int lc = lane & 15, lg = lane >> 4;

  const u16* Ao = A + (size_t)m0 * K;
  const u16* Bo = BT + (size_t)n0 * K;

  f32x4 acc[4][4] = {};
  stage128x32(Ao, (size_t)K * 2, sS[0], lane, wid);
  stage128x32(Bo, (size_t)K * 2, sS[2], lane, wid);
  __syncthreads();
  int cur = 0;
  int NT = K >> 5;
  for (int kt = 0; kt < NT; kt++) {
    if (kt + 1 < NT) {
      stage128x32(Ao + (kt + 1) * 32, (size_t)K * 2, sS[cur ^ 1], lane, wid);
      stage128x32(Bo + (kt + 1) * 32, (size_t)K * 2, sS[2 + (cur ^ 1)], lane, wid);
    }
    bf16x8 af[4], bfr[4];
#pragma unroll
    for (int i = 0; i < 4; i++) af[i] = read64(sS[cur], wm * 64 + i * 16 + lc, lg * 16);
#pragma unroll
    for (int j = 0; j < 4; j++) bfr[j] = read64(sS[2 + cur], wn * 64 + j * 16 + lc, lg * 16);
    __builtin_amdgcn_s_setprio(1);
#pragma unroll
    for (int i = 0; i < 4; i++)
#pragma unroll
      for (int j = 0; j < 4; j++)
        acc[i][j] = __builtin_amdgcn_mfma_f32_16x16x32_bf16(af[i], bfr[j], acc[i][j], 0, 0, 0);
    __builtin_amdgcn_s_setprio(0);
    __syncthreads();
    cur ^= 1;
  }

  int rg = lane >> 4;
  if (QKV && n0 >= 2 * DDIM) {
    // V third -> LDS transpose (32KB trS[vcol][256B], 16B-XOR swizzle) -> vT
    char* trS = (char*)&sS[0][0];
#pragma unroll
    for (int i = 0; i < 4; i++) {
      int rb = (wm * 64 + i * 16 + rg * 4) * 2;   // row byte offset, 8B-aligned
#pragma unroll
      for (int j = 0; j < 4; j++) {
        int vc = wn * 64 + j * 16 + lc;
        float bv = bias[n0 + vc];
        u16 tmp[4];
#pragma unroll
        for (int r = 0; r < 4; r++) tmp[r] = f2bf(acc[i][j][r] + bv);
        *reinterpret_cast<u64*>(trS + vc * 256 + (rb ^ ((vc & 7) << 4))) =
            *reinterpret_cast<u64*>(tmp);
      }
    }
    __syncthreads();
    int bb = m0 >> 11, l0 = m0 & (LLEN - 1);
    int t7 = t & 7, tv = t >> 3;                  // tv in 0..31
#pragma unroll
    for (int p = 0; p < 4; p++) {
      int vc = p * 32 + tv;
      size_t vrow = ((size_t)bb * (HH * DH) + (n0 - 2 * DDIM) + vc) * LLEN + l0;
#pragma unroll
      for (int half = 0; half < 2; half++) {
        int rowbyte = t7 * 16 + half * 128;       // 16B-aligned
        u64x2 v = *reinterpret_cast<const u64x2*>(
            trS + vc * 256 + (rowbyte ^ ((vc & 7) << 4)));
        *reinterpret_cast<u64x2*>(&vT[vrow + rowbyte / 2]) = v;
      }
    }
    return;
  }
#pragma unroll
  for (int i = 0; i < 4; i++) {
#pragma unroll
    for (int j = 0; j < 4; j++) {
      int col = n0 + wn * 64 + j * 16 + lc;
      float bv = bias[col];
#pragma unroll
      for (int r = 0; r < 4; r++) {
        int row = m0 + wm * 64 + i * 16 + rg * 4 + r;
        float v = acc[i][j][r] + bv;
        if (BF16_OUT)
          ((u16*)C)[(size_t)row * N + col] = f2bf(v);
        else
          ((float*)C)[(size_t)row * N + col] = v;
      }
    }
  }
}

// ---------------- flash attention, swapped QK^T, counted-vmcnt pipeline ----------------
// Key permutation: QK^T mfma #blk uses K rows f(blk,m)=32*(blk>>1)+8*(m>>2)+
// 4*(blk&1)+(m&3). Lane (lc,lg) owns S[q=qb+lc][key=f(blk,lg*4+r)] in
// sv[blk][r] == PV A-frag element order — P->PV is in-lane bf16 casts only.
// Pipeline: 6 VMEM ops per wave per tile; s_waitcnt vmcnt(6) keeps the next
// tile's loads in flight. Main loop manually unrolled x2 (literal buffer
// indices -> compile-time LDS offsets, no cur-flip arithmetic).
// XCD remap: lin%8 == XCD (heuristic); each XCD gets 4 contiguous bh ->
// K/V working set 2MB < 4MB L2.
__global__ __launch_bounds__(256, 4) void k_attn(const u16* __restrict__ qkv,
                                                 const u16* __restrict__ vT,
                                                 const f32x2* __restrict__ ppk,
                                                 const float* __restrict__ rscale_p,
                                                 u16* __restrict__ attn_out) {
  __shared__ __attribute__((aligned(16))) u16 kS[2][64 * 64];
  __shared__ __attribute__((aligned(16))) u16 vS[2][64 * 64];
  __shared__ __attribute__((aligned(16))) float ppS[2][128];

  int lin = blockIdx.y * 32 + blockIdx.x;
  int xcd = lin & 7, slot = lin >> 3;
  int bh = xcd * 4 + (slot >> 5);
  int q0 = (slot & 31) * 64;
  int b = bh >> 4, h = bh & 15;
  int t = threadIdx.x, lane = t & 63, wid = t >> 6;
  int qb = q0 + wid * 16;
  int lc = lane & 15, lg = lane >> 4;

  const float rs2 = (*rscale_p) * LOG2E;
  const float c1 = 0.125f * LOG2E;
  const f32x2* pprow = ppk + (size_t)bh * LLEN;
  const float* pprowf = (const float*)pprow;

  // Q B-fragment: lane holds Q[qb+lc][dh=lg*8+j]
  bf16x8 qf0, qf1;
  {
    const u16* qp = &qkv[(size_t)(b * LLEN + qb + lc) * N3 + h * DH + lg * 8];
    qf0 = *reinterpret_cast<const bf16x8*>(qp);
    qf1 = *reinterpret_cast<const bf16x8*>(qp + 32);
  }
  float wq = 2.f * rs2 * pprow[qb + lc].x;   // per-lane scalar (q = lc)

  const u16* kg = qkv + (size_t)(b * LLEN) * N3 + DDIM + h * DH;  // rows: key
  const u16* vg = vT + (size_t)bh * DH * LLEN;                    // rows: dh

  // prologue: stage tile 0 (6 VMEM ops per wave)
  stage64(kg, (size_t)N3 * 2, kS[0], lane, wid);
  stage64(vg, (size_t)LLEN * 2, vS[0], lane, wid);
  gl4(pprowf + lane, &ppS[0][0]);
  gl4(pprowf + 64 + lane, &ppS[0][64]);

  f32x4 o[4] = {};
  float mrow = -1e30f, lrow = 0.f;
  int arow = ((lc >> 2) << 3) | (lc & 3);    // f(blk,lc) base

#define ATTN_STEP(KB, CUR)                                                     \
  do {                                                                         \
    if ((KB) + 64 < LLEN) {                                                    \
      stage64(kg + (size_t)((KB) + 64) * N3, (size_t)N3 * 2, kS[(CUR) ^ 1],    \
              lane, wid);                                                      \
      stage64(vg + (KB) + 64, (size_t)LLEN * 2, vS[(CUR) ^ 1], lane, wid);     \
      const float* pt_ = pprowf + (size_t)((KB) + 64) * 2;                     \
      gl4(pt_ + lane, &ppS[(CUR) ^ 1][0]);                                     \
      gl4(pt_ + 64 + lane, &ppS[(CUR) ^ 1][64]);                               \
      asm volatile("s_waitcnt vmcnt(6)" ::: "memory");                         \
    } else {                                                                   \
      asm volatile("s_waitcnt vmcnt(0)" ::: "memory");                         \
    }                                                                          \
    __builtin_amdgcn_s_barrier();                                              \
    f32x4 sv[4];                                                               \
    _Pragma("unroll") for (int blk = 0; blk < 4; blk++) {                      \
      int krow = arow + ((blk & 2) << 4) + ((blk & 1) << 2);                   \
      bf16x8 kf0 = read128s(kS[CUR], krow, lg * 16);                           \
      bf16x8 kf1 = read128s(kS[CUR], krow, 64 + lg * 16);                      \
      f32x4 z = {};                                                            \
      __builtin_amdgcn_s_setprio(1);                                           \
      z = __builtin_amdgcn_mfma_f32_16x16x32_bf16(kf0, qf0, z, 0, 0, 0);       \
      z = __builtin_amdgcn_mfma_f32_16x16x32_bf16(kf1, qf1, z, 0, 0, 0);       \
      __builtin_amdgcn_s_setprio(0);                                           \
      sv[blk] = z;                                                             \
    }                                                                          \
    {                                                                          \
      const float* pt_ = &ppS[CUR][0];                                         \
      _Pragma("unroll") for (int blk = 0; blk < 4; blk++) {                    \
        int off2 = (((blk & 2) << 4) + ((blk & 1) << 2) + lg * 8) * 2;         \
        f32x4 p0 = *reinterpret_cast<const f32x4*>(pt_ + off2);                \
        f32x4 p1 = *reinterpret_cast<const f32x4*>(pt_ + off2 + 4);            \
        sv[blk][0] = fmaf(sv[blk][0], c1, fmaf(wq, p0.x, p0.y));               \
        sv[blk][1] = fmaf(sv[blk][1], c1, fmaf(wq, p0.z, p0.w));               \
        sv[blk][2] = fmaf(sv[blk][2], c1, fmaf(wq, p1.x, p1.y));               \
        sv[blk][3] = fmaf(sv[blk][3], c1, fmaf(wq, p1.z, p1.w));               \
      }                                                                        \
    }                                                                          \
    float rm = sv[0][0];                                                       \
    _Pragma("unroll") for (int blk = 0; blk < 4; blk++)                        \
        _Pragma("unroll") for (int r = 0; r < 4; r++)                          \
            rm = fmaxf(rm, sv[blk][r]);                                        \
    rm = fmaxf(rm, __shfl_xor(rm, 16, 64));                                    \
    rm = fmaxf(rm, __shfl_xor(rm, 32, 64));                                    \
    if (!__all(rm <= mrow + 8.f)) {                                            \
      float mn = fmaxf(mrow, rm);                                              \
      float al = __builtin_amdgcn_exp2f(mrow - mn);                            \
      mrow = mn;                                                               \
      lrow *= al;                                                              \
      float ao0 = __shfl(al, lg * 4 + 0, 16);                                  \
      float ao1 = __shfl(al, lg * 4 + 1, 16);                                  \
      float ao2 = __shfl(al, lg * 4 + 2, 16);                                  \
      float ao3 = __shfl(al, lg * 4 + 3, 16);                                  \
      _Pragma("unroll") for (int d = 0; d < 4; d++) {                          \
        o[d][0] *= ao0; o[d][1] *= ao1; o[d][2] *= ao2; o[d][3] *= ao3;        \
      }                                                                        \
    }                                                                          \
    float ssum = 0.f;                                                          \
    _Pragma("unroll") for (int blk = 0; blk < 4; blk++)                        \
        _Pragma("unroll") for (int r = 0; r < 4; r++) {                        \
      float p = __builtin_amdgcn_exp2f(sv[blk][r] - mrow);                     \
      sv[blk][r] = p;                                                          \
      ssum += p;                                                               \
    }                                                                          \
    ssum += __shfl_xor(ssum, 16, 64);                                          \
    ssum += __shfl_xor(ssum, 32, 64);                                          \
    lrow += ssum;                                                              \
    bf16x8 pa0, pa1;                                                           \
    _Pragma("unroll") for (int r = 0; r < 4; r++) {                            \
      pa0[r] = (__bf16)sv[0][r];                                               \
      pa0[4 + r] = (__bf16)sv[1][r];                                           \
      pa1[r] = (__bf16)sv[2][r];                                               \
      pa1[4 + r] = (__bf16)sv[3][r];                                           \
    }                                                                          \
    _Pragma("unroll") for (int d = 0; d < 4; d++) {                            \
      bf16x8 vb0 = read128s(vS[CUR], d * 16 + lc, lg * 16);                    \
      bf16x8 vb1 = read128s(vS[CUR], d * 16 + lc, 64 + lg * 16);               \
      __builtin_amdgcn_s_setprio(1);                                           \
      o[d] = __builtin_amdgcn_mfma_f32_16x16x32_bf16(pa0, vb0, o[d], 0, 0, 0); \
      o[d] = __builtin_amdgcn_mfma_f32_16x16x32_bf16(pa1, vb1, o[d], 0, 0, 0); \
      __builtin_amdgcn_s_setprio(0);                                           \
    }                                                                          \
    __builtin_amdgcn_s_barrier();                                              \
  } while (0)

  for (int kt = 0; kt < LLEN / 64; kt += 2) {
    ATTN_STEP(kt * 64, 0);
    ATTN_STEP(kt * 64 + 64, 1);
  }
#undef ATTN_STEP

  // epilogue: O rows are q=qb+lg*4+r, cols dh=d*16+lc; l lives at lane lc=q
  float linv = 1.0f / lrow;
  float li0 = __shfl(linv, lg * 4 + 0, 16);
  float li1 = __shfl(linv, lg * 4 + 1, 16);
  float li2 = __shfl(linv, lg * 4 + 2, 16);
  float li3 = __shfl(linv, lg * 4 + 3, 16);
#pragma unroll
  for (int d = 0; d < 4; d++) {
    int col = h * DH + d * 16 + lc;
    size_t base = (size_t)(b * LLEN + qb + lg * 4) * DDIM + col;
    attn_out[base] = f2bf(o[d][0] * li0);
    attn_out[base + DDIM] = f2bf(o[d][1] * li1);
    attn_out[base + 2 * DDIM] = f2bf(o[d][2] * li2);
    attn_out[base + 3 * DDIM] = f2bf(o[d][3] * li3);
  }
}

extern "C" void kernel_launch(void* const* d_in, const int* in_sizes, int n_in,
                              void* d_out, int out_size, void* d_ws, size_t ws_size,
                              hipStream_t stream) {
  const float* x       = (const float*)d_in[0];
  const int*   mask    = (const int*)d_in[1];
  const float* W_qkv   = (const float*)d_in[2];
  const float* b_qkv   = (const float*)d_in[3];
  const float* W_out   = (const float*)d_in[4];
  const float* b_out   = (const float*)d_in[5];
  const float* W_phase = (const float*)d_in[6];
  const float* b_phase = (const float*)d_in[7];
  const float* rscale  = (const float*)d_in[8];
  const float* pscale  = (const float*)d_in[9];
  float* out = (float*)d_out;

  char* ws = (char*)d_ws;
  u16* x_bf     = (u16*)(ws + 0);           //  8.0 MB
  u16* wt_qkv   = (u16*)(ws + 8388608);     //  6.0 MB
  u16* wt_out   = (u16*)(ws + 14680064);    //  2.0 MB
  u16* qkv      = (u16*)(ws + 16777216);    // 24.0 MB (v third unused)
  u16* vT       = (u16*)(ws + 41943040);    //  8.0 MB
  u16* attn_out = (u16*)(ws + 50331648);    //  8.0 MB
  f32x2* ppk    = (f32x2*)(ws + 58720256);  //  0.5 MB

  k_transpose_w<<<dim3(DDIM / 32, N3 / 32), 256, 0, stream>>>(W_qkv, wt_qkv, DDIM, N3);
  k_transpose_w<<<dim3(DDIM / 32, DDIM / 32), 256, 0, stream>>>(W_out, wt_out, DDIM, DDIM);
  k_phase<<<MTOT, 256, 0, stream>>>(x, W_phase, b_phase, pscale, rscale, mask, ppk, x_bf);
  k_gemm<true, true><<<dim3(MTOT / 128, N3 / 128), 256, 0, stream>>>(
      x_bf, wt_qkv, b_qkv, qkv, vT, MTOT, N3, DDIM);
  k_attn<<<dim3(LLEN / 64, BB * HH), 256, 0, stream>>>(
      qkv, vT, ppk, rscale, attn_out);
  k_gemm<false, false><<<dim3(MTOT / 128, DDIM / 128), 256, 0, stream>>>(
      attn_out, wt_out, b_out, out, nullptr, MTOT, DDIM, DDIM);
}

// Round 11
// 231.849 us; speedup vs baseline: 1.0739x; 1.0044x over previous
//
#include <hip/hip_runtime.h>

typedef unsigned short u16;
typedef unsigned int u32;
typedef unsigned long long u64;
typedef __attribute__((ext_vector_type(2))) unsigned long long u64x2;
typedef __attribute__((ext_vector_type(4))) unsigned short u16x4;
typedef __attribute__((ext_vector_type(8))) __bf16 bf16x8;
typedef __attribute__((ext_vector_type(4))) float f32x4;
typedef __attribute__((ext_vector_type(2))) float f32x2;

#define DEV static __device__ __forceinline__
#define LOG2E 1.4426950408889634f

DEV u16 f2bf(float f) { __bf16 h = (__bf16)f; return __builtin_bit_cast(u16, h); }

// Problem constants
#define BB   2
#define LLEN 2048
#define DDIM 1024
#define HH   16
#define DH   64
#define MTOT 4096   // B*L
#define N3   3072   // 3*D

// ---------------- async global->LDS ----------------
DEV void gl16(const void* g, void* l) {
  __builtin_amdgcn_global_load_lds(
      (const __attribute__((address_space(1))) void*)g,
      (__attribute__((address_space(3))) void*)l, 16, 0, 0);
}
DEV void gl4(const void* g, void* l) {
  __builtin_amdgcn_global_load_lds(
      (const __attribute__((address_space(1))) void*)g,
      (__attribute__((address_space(3))) void*)l, 4, 0, 0);
}

// Stage a 64-row x 128B tile into linear LDS with XOR swizzle on row bits
// {0,1,3}: LDS[row*128 + cb] = G[row][cb ^ (swz3(row)<<4)],
// swz3(row) = (row&3) | (((row>>3)&1)<<2).
DEV void stage64(const u16* org, size_t gsb, u16* lds, int lane, int wid) {
#pragma unroll
  for (int j = 0; j < 2; j++) {
    int inst = wid * 2 + j;
    int r8 = lane >> 3;                      // row&7
    int row = inst * 8 + r8;
    int s = (r8 & 3) | ((inst & 1) << 2);    // == swz3(row)
    const char* src = (const char*)org + (size_t)row * gsb +
                      (((lane & 7) ^ s) << 4);
    gl16(src, (char*)lds + inst * 1024);
  }
}
DEV bf16x8 read128s(const u16* tile, int row, int colb) {
  return *reinterpret_cast<const bf16x8*>(
      (const char*)tile + row * 128 +
      (colb ^ (((row & 3) | (((row >> 3) & 1) << 2)) << 4)));
}

// Stage a ROWS-row x 64B tile: LDS[row*64 + cb] = G[row][cb ^ ((row&3)<<4)].
template <int ROWS>
DEV void stageR32(const u16* org, size_t gsb, u16* lds, int lane, int wid) {
#pragma unroll
  for (int j = 0; j < ROWS / 64; j++) {
    int inst = wid + j * 4;
    int r16 = lane >> 2;
    const char* src = (const char*)org + (size_t)(inst * 16 + r16) * gsb +
                      ((((lane & 3) ^ (r16 & 3))) << 4);
    gl16(src, (char*)lds + inst * 1024);
  }
}
DEV bf16x8 read64(const u16* tile, int row, int colb) {
  return *reinterpret_cast<const bf16x8*>(
      (const char*)tile + row * 64 + (colb ^ ((row & 3) << 4)));
}

// ---------------- both W transposes in one launch ----------------
// y < 96: W_qkv [1024][3072]; else W_out [1024][1024].
__global__ __launch_bounds__(256) void k_transpose_w2(const float* __restrict__ Wq,
                                                      const float* __restrict__ Wo,
                                                      u16* __restrict__ WTq,
                                                      u16* __restrict__ WTo) {
  __shared__ float s[32][33];
  int y = blockIdx.y;
  const float* W;
  u16* WT;
  int N, n0;
  if (y < 96) { W = Wq; WT = WTq; N = N3; n0 = y * 32; }
  else        { W = Wo; WT = WTo; N = DDIM; n0 = (y - 96) * 32; }
  int k0 = blockIdx.x * 32;
  int tx = threadIdx.x & 31, ty = threadIdx.x >> 5;
#pragma unroll
  for (int i = 0; i < 4; i++)
    s[ty + i * 8][tx] = W[(k0 + ty + i * 8) * (size_t)N + n0 + tx];
  __syncthreads();
#pragma unroll
  for (int i = 0; i < 4; i++)
    WT[(size_t)(n0 + ty + i * 8) * DDIM + k0 + tx] = f2bf(s[tx][ty + i * 8]);
}

// ---------------- phase + x->bf16 fused ----------------
__global__ __launch_bounds__(256) void k_phase(const float* __restrict__ x,
                                               const float* __restrict__ Wp,
                                               const float* __restrict__ bp,
                                               const float* __restrict__ pscale,
                                               const float* __restrict__ rscale,
                                               const int* __restrict__ mask,
                                               f32x2* __restrict__ ppk,
                                               u16* __restrict__ x_bf) {
  int m = blockIdx.x;
  int t = threadIdx.x;
  const float* xr = x + (size_t)m * DDIM;
  u16* xbr = x_bf + (size_t)m * DDIM;
  // coalesced x -> bf16
  {
    f32x4 xv = *reinterpret_cast<const f32x4*>(xr + t * 4);
    u16x4 o;
    o.x = f2bf(xv.x); o.y = f2bf(xv.y); o.z = f2bf(xv.z); o.w = f2bf(xv.w);
    *reinterpret_cast<u16x4*>(xbr + t * 4) = o;
  }
  int h = t & 15, j = t >> 4;
  const float* wpb = Wp + h;
  float acc = 0.f;
#pragma unroll 4
  for (int kk4 = 0; kk4 < 16; kk4++) {
    int k0 = j * 64 + kk4 * 4;
    f32x4 xv = *reinterpret_cast<const f32x4*>(xr + k0);
    acc = fmaf(xv.x, wpb[(k0 + 0) * HH], acc);
    acc = fmaf(xv.y, wpb[(k0 + 1) * HH], acc);
    acc = fmaf(xv.z, wpb[(k0 + 2) * HH], acc);
    acc = fmaf(xv.w, wpb[(k0 + 3) * HH], acc);
  }
  __shared__ float s[16][17];
  s[j][h] = acc;
  __syncthreads();
  if (t < 16) {
    float sum = 0.f;
#pragma unroll
    for (int jj = 0; jj < 16; jj++) sum += s[jj][t];
    float v = tanhf((*pscale) * (sum + bp[t]));
    int b = m >> 11, l = m & (LLEN - 1);
    float kb = (mask[m] == 0) ? -1.0e9f : (-(*rscale) * LOG2E) * v * v;
    f32x2 o; o.x = v; o.y = kb;
    ppk[((size_t)(b * HH + t)) * LLEN + l] = o;
  }
}

// ---------------- 128xBN bf16 MFMA GEMM (dbuf + global_load_lds) ----------------
// QKV mode (BN=128): V-third tiles go through an LDS transpose (reusing the
// staging buffers after the final barrier) to vT[b][h][dh][l], coalesced.
template <bool BF16_OUT, bool QKV, int BN>
__global__ __launch_bounds__(256) void k_gemm(const u16* __restrict__ A,
                                              const u16* __restrict__ BT,
                                              const float* __restrict__ bias,
                                              void* __restrict__ C,
                                              u16* __restrict__ vT,
                                              int M, int N, int K) {
  __shared__ __attribute__((aligned(16))) u16 sA[2][128 * 32];
  __shared__ __attribute__((aligned(16))) u16 sB[2][BN * 32];
  constexpr int NW = BN / 32;                    // per-wave n-frags
  int m0 = blockIdx.x * 128, n0 = blockIdx.y * BN;
  int t = threadIdx.x, lane = t & 63, wid = t >> 6;
  int wm = wid >> 1, wn = wid & 1;
  int lc = lane & 15, lg = lane >> 4;

  const u16* Ao = A + (size_t)m0 * K;
  const u16* Bo = BT + (size_t)n0 * K;

  f32x4 acc[4][NW] = {};
  stageR32<128>(Ao, (size_t)K * 2, sA[0], lane, wid);
  stageR32<BN>(Bo, (size_t)K * 2, sB[0], lane, wid);
  __syncthreads();
  int cur = 0;
  int NT = K >> 5;
  for (int kt = 0; kt < NT; kt++) {
    if (kt + 1 < NT) {
      stageR32<128>(Ao + (kt + 1) * 32, (size_t)K * 2, sA[cur ^ 1], lane, wid);
      stageR32<BN>(Bo + (kt + 1) * 32, (size_t)K * 2, sB[cur ^ 1], lane, wid);
    }
    bf16x8 af[4], bfr[NW];
#pragma unroll
    for (int i = 0; i < 4; i++) af[i] = read64(sA[cur], wm * 64 + i * 16 + lc, lg * 16);
#pragma unroll
    for (int j = 0; j < NW; j++) bfr[j] = read64(sB[cur], wn * (BN / 2) + j * 16 + lc, lg * 16);
    __builtin_amdgcn_s_setprio(1);
#pragma unroll
    for (int i = 0; i < 4; i++)
#pragma unroll
      for (int j = 0; j < NW; j++)
        acc[i][j] = __builtin_amdgcn_mfma_f32_16x16x32_bf16(af[i], bfr[j], acc[i][j], 0, 0, 0);
    __builtin_amdgcn_s_setprio(0);
    __syncthreads();
    cur ^= 1;
  }

  int rg = lane >> 4;
  if constexpr (QKV) {
    if (n0 >= 2 * DDIM) {
      // V third -> LDS transpose (16B-XOR swizzle; vc<64 in sA, vc>=64 in sB)
      char* halfW = wn ? (char*)&sB[0][0] : (char*)&sA[0][0];
#pragma unroll
      for (int i = 0; i < 4; i++) {
        int rb = (wm * 64 + i * 16 + rg * 4) * 2;   // row byte offset
#pragma unroll
        for (int j = 0; j < NW; j++) {
          int vcl = j * 16 + lc;                    // 0..63 within half
          int vc = wn * 64 + vcl;
          float bv = bias[n0 + vc];
          u16 tmp[4];
#pragma unroll
          for (int r = 0; r < 4; r++) tmp[r] = f2bf(acc[i][j][r] + bv);
          *reinterpret_cast<u64*>(halfW + vcl * 256 + (rb ^ ((vc & 7) << 4))) =
              *reinterpret_cast<u64*>(tmp);
        }
      }
      __syncthreads();
      int bb = m0 >> 11, l0 = m0 & (LLEN - 1);
      int t7 = t & 7, tv = t >> 3;                  // tv in 0..31
#pragma unroll
      for (int p = 0; p < 4; p++) {
        int vc = p * 32 + tv;
        char* halfR = (vc & 64) ? (char*)&sB[0][0] : (char*)&sA[0][0];
        int vcl = vc & 63;
        size_t vrow = ((size_t)bb * (HH * DH) + (n0 - 2 * DDIM) + vc) * LLEN + l0;
#pragma unroll
        for (int half = 0; half < 2; half++) {
          int rowbyte = t7 * 16 + half * 128;       // 16B-aligned
          u64x2 v = *reinterpret_cast<const u64x2*>(
              halfR + vcl * 256 + (rowbyte ^ ((vc & 7) << 4)));
          *reinterpret_cast<u64x2*>(&vT[vrow + rowbyte / 2]) = v;
        }
      }
      return;
    }
  }
#pragma unroll
  for (int i = 0; i < 4; i++) {
#pragma unroll
    for (int j = 0; j < NW; j++) {
      int col = n0 + wn * (BN / 2) + j * 16 + lc;
      float bv = bias[col];
#pragma unroll
      for (int r = 0; r < 4; r++) {
        int row = m0 + wm * 64 + i * 16 + rg * 4 + r;
        float v = acc[i][j][r] + bv;
        if (BF16_OUT)
          ((u16*)C)[(size_t)row * N + col] = f2bf(v);
        else
          ((float*)C)[(size_t)row * N + col] = v;
      }
    }
  }
}

// ---------------- flash attention, swapped QK^T, counted-vmcnt pipeline ----------------
// Key permutation: QK^T mfma #blk uses K rows f(blk,m)=32*(blk>>1)+8*(m>>2)+
// 4*(blk&1)+(m&3). Lane (lc,lg) owns S[q=qb+lc][key=f(blk,lg*4+r)] in
// sv[blk][r] == PV A-frag element order — P->PV is in-lane bf16 casts only.
// Row-sum l is computed by 2 extra MFMAs against a constant ones-B-fragment:
// lrow4 reg r holds l for q=qb+lg*4+r — the SAME layout as o[d], so rescale
// and epilogue need no cross-lane moves (deletes 16 adds + 6 shfl per tile).
// Pipeline: 6 VMEM ops per wave per tile; vmcnt(6) keeps next tile in flight.
// XCD remap: lin%8 == XCD; each XCD gets 4 contiguous bh (K/V set 2MB < L2).
__global__ __launch_bounds__(256, 4) void k_attn(const u16* __restrict__ qkv,
                                                 const u16* __restrict__ vT,
                                                 const f32x2* __restrict__ ppk,
                                                 const float* __restrict__ rscale_p,
                                                 u16* __restrict__ attn_out) {
  __shared__ __attribute__((aligned(16))) u16 kS[2][64 * 64];
  __shared__ __attribute__((aligned(16))) u16 vS[2][64 * 64];
  __shared__ __attribute__((aligned(16))) float ppS[2][128];

  int lin = blockIdx.y * 32 + blockIdx.x;
  int xcd = lin & 7, slot = lin >> 3;
  int bh = xcd * 4 + (slot >> 5);
  int q0 = (slot & 31) * 64;
  int b = bh >> 4, h = bh & 15;
  int t = threadIdx.x, lane = t & 63, wid = t >> 6;
  int qb = q0 + wid * 16;
  int lc = lane & 15, lg = lane >> 4;

  const float rs2 = (*rscale_p) * LOG2E;
  const float c1 = 0.125f * LOG2E;
  const f32x2* pprow = ppk + (size_t)bh * LLEN;
  const float* pprowf = (const float*)pprow;

  bf16x8 ONES;
#pragma unroll
  for (int j = 0; j < 8; j++) ONES[j] = (__bf16)1.0f;

  // Q B-fragment: lane holds Q[qb+lc][dh=lg*8+j]
  bf16x8 qf0, qf1;
  {
    const u16* qp = &qkv[(size_t)(b * LLEN + qb + lc) * N3 + h * DH + lg * 8];
    qf0 = *reinterpret_cast<const bf16x8*>(qp);
    qf1 = *reinterpret_cast<const bf16x8*>(qp + 32);
  }
  float wq = 2.f * rs2 * pprow[qb + lc].x;   // per-lane scalar (q = lc)

  const u16* kg = qkv + (size_t)(b * LLEN) * N3 + DDIM + h * DH;  // rows: key
  const u16* vg = vT + (size_t)bh * DH * LLEN;                    // rows: dh

  // prologue: stage tile 0 (6 VMEM ops per wave)
  stage64(kg, (size_t)N3 * 2, kS[0], lane, wid);
  stage64(vg, (size_t)LLEN * 2, vS[0], lane, wid);
  gl4(pprowf + lane, &ppS[0][0]);
  gl4(pprowf + 64 + lane, &ppS[0][64]);

  f32x4 o[4] = {};
  f32x4 lrow4 = {};
  float mrow = -1e30f;
  int arow = ((lc >> 2) << 3) | (lc & 3);    // f(blk,lc) base

#define ATTN_STEP(KB, CUR)                                                     \
  do {                                                                         \
    if ((KB) + 64 < LLEN) {                                                    \
      stage64(kg + (size_t)((KB) + 64) * N3, (size_t)N3 * 2, kS[(CUR) ^ 1],    \
              lane, wid);                                                      \
      stage64(vg + (KB) + 64, (size_t)LLEN * 2, vS[(CUR) ^ 1], lane, wid);     \
      const float* pt_ = pprowf + (size_t)((KB) + 64) * 2;                     \
      gl4(pt_ + lane, &ppS[(CUR) ^ 1][0]);                                     \
      gl4(pt_ + 64 + lane, &ppS[(CUR) ^ 1][64]);                               \
      asm volatile("s_waitcnt vmcnt(6)" ::: "memory");                         \
    } else {                                                                   \
      asm volatile("s_waitcnt vmcnt(0)" ::: "memory");                         \
    }                                                                          \
    __builtin_amdgcn_s_barrier();                                              \
    f32x4 sv[4];                                                               \
    _Pragma("unroll") for (int blk = 0; blk < 4; blk++) {                      \
      int krow = arow + ((blk & 2) << 4) + ((blk & 1) << 2);                   \
      bf16x8 kf0 = read128s(kS[CUR], krow, lg * 16);                           \
      bf16x8 kf1 = read128s(kS[CUR], krow, 64 + lg * 16);                      \
      f32x4 z = {};                                                            \
      __builtin_amdgcn_s_setprio(1);                                           \
      z = __builtin_amdgcn_mfma_f32_16x16x32_bf16(kf0, qf0, z, 0, 0, 0);       \
      z = __builtin_amdgcn_mfma_f32_16x16x32_bf16(kf1, qf1, z, 0, 0, 0);       \
      __builtin_amdgcn_s_setprio(0);                                           \
      sv[blk] = z;                                                             \
    }                                                                          \
    {                                                                          \
      const float* pt_ = &ppS[CUR][0];                                         \
      _Pragma("unroll") for (int blk = 0; blk < 4; blk++) {                    \
        int off2 = (((blk & 2) << 4) + ((blk & 1) << 2) + lg * 8) * 2;         \
        f32x4 p0 = *reinterpret_cast<const f32x4*>(pt_ + off2);                \
        f32x4 p1 = *reinterpret_cast<const f32x4*>(pt_ + off2 + 4);            \
        sv[blk][0] = fmaf(sv[blk][0], c1, fmaf(wq, p0.x, p0.y));               \
        sv[blk][1] = fmaf(sv[blk][1], c1, fmaf(wq, p0.z, p0.w));               \
        sv[blk][2] = fmaf(sv[blk][2], c1, fmaf(wq, p1.x, p1.y));               \
        sv[blk][3] = fmaf(sv[blk][3], c1, fmaf(wq, p1.z, p1.w));               \
      }                                                                        \
    }                                                                          \
    /* tile max: v_max3 triples, then 2 shfl */                                \
    float a_ = fmaxf(fmaxf(sv[0][0], sv[0][1]), sv[0][2]);                     \
    float b_ = fmaxf(fmaxf(sv[0][3], sv[1][0]), sv[1][1]);                     \
    float c_ = fmaxf(fmaxf(sv[1][2], sv[1][3]), sv[2][0]);                     \
    float d_ = fmaxf(fmaxf(sv[2][1], sv[2][2]), sv[2][3]);                     \
    float e_ = fmaxf(fmaxf(sv[3][0], sv[3][1]), sv[3][2]);                     \
    float rm = fmaxf(fmaxf(a_, b_), c_);                                       \
    float rm2 = fmaxf(fmaxf(d_, e_), sv[3][3]);                                \
    rm = fmaxf(rm, rm2);                                                       \
    rm = fmaxf(rm, __shfl_xor(rm, 16, 64));                                    \
    rm = fmaxf(rm, __shfl_xor(rm, 32, 64));                                    \
    if (!__all(rm <= mrow + 8.f)) {                                            \
      float mn = fmaxf(mrow, rm);                                              \
      float al = __builtin_amdgcn_exp2f(mrow - mn);                            \
      mrow = mn;                                                               \
      float ao0 = __shfl(al, lg * 4 + 0, 16);                                  \
      float ao1 = __shfl(al, lg * 4 + 1, 16);                                  \
      float ao2 = __shfl(al, lg * 4 + 2, 16);                                  \
      float ao3 = __shfl(al, lg * 4 + 3, 16);                                  \
      _Pragma("unroll") for (int d = 0; d < 4; d++) {                          \
        o[d][0] *= ao0; o[d][1] *= ao1; o[d][2] *= ao2; o[d][3] *= ao3;        \
      }                                                                        \
      lrow4[0] *= ao0; lrow4[1] *= ao1; lrow4[2] *= ao2; lrow4[3] *= ao3;      \
    }                                                                          \
    _Pragma("unroll") for (int blk = 0; blk < 4; blk++)                        \
        _Pragma("unroll") for (int r = 0; r < 4; r++)                          \
            sv[blk][r] = __builtin_amdgcn_exp2f(sv[blk][r] - mrow);            \
    bf16x8 pa0, pa1;                                                           \
    _Pragma("unroll") for (int r = 0; r < 4; r++) {                            \
      pa0[r] = (__bf16)sv[0][r];                                               \
      pa0[4 + r] = (__bf16)sv[1][r];                                           \
      pa1[r] = (__bf16)sv[2][r];                                               \
      pa1[4 + r] = (__bf16)sv[3][r];                                           \
    }                                                                          \
    _Pragma("unroll") for (int d = 0; d < 4; d++) {                            \
      bf16x8 vb0 = read128s(vS[CUR], d * 16 + lc, lg * 16);                    \
      bf16x8 vb1 = read128s(vS[CUR], d * 16 + lc, 64 + lg * 16);               \
      __builtin_amdgcn_s_setprio(1);                                           \
      o[d] = __builtin_amdgcn_mfma_f32_16x16x32_bf16(pa0, vb0, o[d], 0, 0, 0); \
      o[d] = __builtin_amdgcn_mfma_f32_16x16x32_bf16(pa1, vb1, o[d], 0, 0, 0); \
      __builtin_amdgcn_s_setprio(0);                                           \
    }                                                                          \
    /* row-sum l += P . ones, in o-layout */                                   \
    lrow4 = __builtin_amdgcn_mfma_f32_16x16x32_bf16(pa0, ONES, lrow4, 0, 0, 0);\
    lrow4 = __builtin_amdgcn_mfma_f32_16x16x32_bf16(pa1, ONES, lrow4, 0, 0, 0);\
    __builtin_amdgcn_s_barrier();                                              \
  } while (0)

  for (int kt = 0; kt < LLEN / 64; kt += 2) {
    ATTN_STEP(kt * 64, 0);
    ATTN_STEP(kt * 64 + 64, 1);
  }
#undef ATTN_STEP

  // epilogue: O rows are q=qb+lg*4+r, cols dh=d*16+lc; lrow4 same layout
  float li0 = 1.0f / lrow4[0];
  float li1 = 1.0f / lrow4[1];
  float li2 = 1.0f / lrow4[2];
  float li3 = 1.0f / lrow4[3];
#pragma unroll
  for (int d = 0; d < 4; d++) {
    int col = h * DH + d * 16 + lc;
    size_t base = (size_t)(b * LLEN + qb + lg * 4) * DDIM + col;
    attn_out[base] = f2bf(o[d][0] * li0);
    attn_out[base + DDIM] = f2bf(o[d][1] * li1);
    attn_out[base + 2 * DDIM] = f2bf(o[d][2] * li2);
    attn_out[base + 3 * DDIM] = f2bf(o[d][3] * li3);
  }
}

extern "C" void kernel_launch(void* const* d_in, const int* in_sizes, int n_in,
                              void* d_out, int out_size, void* d_ws, size_t ws_size,
                              hipStream_t stream) {
  const float* x       = (const float*)d_in[0];
  const int*   mask    = (const int*)d_in[1];
  const float* W_qkv   = (const float*)d_in[2];
  const float* b_qkv   = (const float*)d_in[3];
  const float* W_out   = (const float*)d_in[4];
  const float* b_out   = (const float*)d_in[5];
  const float* W_phase = (const float*)d_in[6];
  const float* b_phase = (const float*)d_in[7];
  const float* rscale  = (const float*)d_in[8];
  const float* pscale  = (const float*)d_in[9];
  float* out = (float*)d_out;

  char* ws = (char*)d_ws;
  u16* x_bf     = (u16*)(ws + 0);           //  8.0 MB
  u16* wt_qkv   = (u16*)(ws + 8388608);     //  6.0 MB
  u16* wt_out   = (u16*)(ws + 14680064);    //  2.0 MB
  u16* qkv      = (u16*)(ws + 16777216);    // 24.0 MB (v third unused)
  u16* vT       = (u16*)(ws + 41943040);    //  8.0 MB
  u16* attn_out = (u16*)(ws + 50331648);    //  8.0 MB
  f32x2* ppk    = (f32x2*)(ws + 58720256);  //  0.5 MB

  k_transpose_w2<<<dim3(DDIM / 32, 128), 256, 0, stream>>>(W_qkv, W_out, wt_qkv, wt_out);
  k_phase<<<MTOT, 256, 0, stream>>>(x, W_phase, b_phase, pscale, rscale, mask, ppk, x_bf);
  k_gemm<true, true, 128><<<dim3(MTOT / 128, N3 / 128), 256, 0, stream>>>(
      x_bf, wt_qkv, b_qkv, qkv, vT, MTOT, N3, DDIM);
  k_attn<<<dim3(LLEN / 64, BB * HH), 256, 0, stream>>>(
      qkv, vT, ppk, rscale, attn_out);
  k_gemm<false, false, 64><<<dim3(MTOT / 128, DDIM / 64), 256, 0, stream>>>(
      attn_out, wt_out, b_out, out, nullptr, MTOT, DDIM, DDIM);
}